// Round 7
// baseline (440.124 us; speedup 1.0000x reference)
//
#include <hip/hip_runtime.h>

#define N_ROWS 8192
#define NX     4096
#define DIM    512
#define BT     128                    // block tile (rows & cols)
#define NT     64                     // N_ROWS / BT
#define NB     (NT * (NT + 1) / 2)    // 2080 live upper-triangle tiles
#define BK     32                     // K elements per stage (64 B per row)
#define GRID   1280                   // 5 blocks/CU x 256 CU, all co-resident

typedef __bf16 bf16_t;
typedef bf16_t bf16x8 __attribute__((ext_vector_type(8)));
typedef float  f32x4  __attribute__((ext_vector_type(4)));

#if __has_builtin(__builtin_amdgcn_exp2f)
  #define EXP2F __builtin_amdgcn_exp2f
#else
  #define EXP2F exp2f
#endif

// ws layout (bytes)  [first 2112 bytes zeroed by hipMemsetAsync each launch]:
//   0     ctr0 u32 | 4 ctr1 u32 | 8 done u32 | 12 pad
//   16    S1acc double
//   24    acc   double
//   32    cvals[5] float (pad to 64)
//   64    colsum[512] float            (ends 2112)
//   2176  sqrow[8192] float            (ends 34944)
//   36864 Zh[8192*512] bf16 row-major  (8 MB)

__device__ __forceinline__ const float* zrow(const float* X, const float* Y, int r) {
    return (r < NX) ? (X + (size_t)r * DIM) : (Y + (size_t)(r - NX) * DIM);
}

__device__ __forceinline__ void gload_lds16(const bf16_t* g, bf16_t* l) {
    __builtin_amdgcn_global_load_lds(
        (__attribute__((address_space(1))) void*)(void*)(g),
        (__attribute__((address_space(3))) void*)(void*)(l), 16, 0, 0);
}

// agent-scope grid barrier; all GRID blocks are co-resident (see launch math)
__device__ __forceinline__ void gbar(unsigned* ctr) {
    __syncthreads();
    if (threadIdx.x == 0) {
        __hip_atomic_fetch_add(ctr, 1u, __ATOMIC_ACQ_REL, __HIP_MEMORY_SCOPE_AGENT);
        while (__hip_atomic_load(ctr, __ATOMIC_ACQUIRE, __HIP_MEMORY_SCOPE_AGENT) < (unsigned)GRID)
            __builtin_amdgcn_s_sleep(2);
    }
    __syncthreads();
}

__global__ __launch_bounds__(256, 5) void k_all(const float* __restrict__ X,
                                                const float* __restrict__ Y,
                                                float* __restrict__ out,
                                                char* __restrict__ ws) {
    unsigned* ctr0   = (unsigned*)(ws + 0);
    unsigned* ctr1   = (unsigned*)(ws + 4);
    unsigned* done   = (unsigned*)(ws + 8);
    double*   S1acc  = (double*)(ws + 16);
    double*   acc    = (double*)(ws + 24);
    float*    cvals  = (float*)(ws + 32);
    float*    colsum = (float*)(ws + 64);
    float*    sqrow  = (float*)(ws + 2176);
    bf16_t*   Zh     = (bf16_t*)(ws + 36864);

    __shared__ bf16_t As[4096];   // 8 KB (reused as float[2048]/double[256] in A/B)
    __shared__ bf16_t Bs[4096];   // 8 KB
    __shared__ float wsum[4];

    int t = threadIdx.x, lane = t & 63, wv = t >> 6;

    // ---------------- Phase A: bf16 convert + sqrow + colsum ----------------
    if (blockIdx.x < 1024) {
        float csum[8] = {0.f,0.f,0.f,0.f,0.f,0.f,0.f,0.f};
        float s1part = 0.f;
        float* cps = (float*)As;           // 4 waves x 512 cols
        #pragma unroll
        for (int rp = 0; rp < 2; ++rp) {
            int row = blockIdx.x * 8 + wv * 2 + rp;
            const float* zr = zrow(X, Y, row) + lane * 8;
            float4 a = *(const float4*)zr;
            float4 c = *(const float4*)(zr + 4);
            bf16x8 h = {(bf16_t)a.x, (bf16_t)a.y, (bf16_t)a.z, (bf16_t)a.w,
                        (bf16_t)c.x, (bf16_t)c.y, (bf16_t)c.z, (bf16_t)c.w};
            *(bf16x8*)(Zh + (size_t)row * DIM + lane * 8) = h;
            csum[0] += a.x; csum[1] += a.y; csum[2] += a.z; csum[3] += a.w;
            csum[4] += c.x; csum[5] += c.y; csum[6] += c.z; csum[7] += c.w;
            float s = a.x*a.x + a.y*a.y + a.z*a.z + a.w*a.w
                    + c.x*c.x + c.y*c.y + c.z*c.z + c.w*c.w;
            #pragma unroll
            for (int off = 32; off > 0; off >>= 1) s += __shfl_down(s, off);
            if (lane == 0) { sqrow[row] = s; s1part += s; }
        }
        #pragma unroll
        for (int j = 0; j < 8; ++j) cps[wv * 512 + lane * 8 + j] = csum[j];
        if (lane == 0) wsum[wv] = s1part;
        __syncthreads();
        #pragma unroll
        for (int cc = 0; cc < 2; ++cc) {
            int c = t * 2 + cc;
            float tot = cps[c] + cps[512 + c] + cps[1024 + c] + cps[1536 + c];
            atomicAdd(&colsum[c], tot);
        }
        if (t == 0) atomicAdd(S1acc, (double)(wsum[0] + wsum[1] + wsum[2] + wsum[3]));
    }
    gbar(ctr0);

    // ---------------- Phase B: block 0 computes bw + cvals ----------------
    if (blockIdx.x == 0) {
        double cs = 0.0;
        for (int c = t; c < 512; c += 256) { double v = colsum[c]; cs += v * v; }
        double* red = (double*)As;
        red[t] = cs; __syncthreads();
        for (int off = 128; off > 0; off >>= 1) {
            if (t < off) red[t] += red[t + off];
            __syncthreads();
        }
        if (t == 0) {
            double S1 = *S1acc;
            double n = (double)N_ROWS;
            double bw = (2.0 * n * S1 - 2.0 * red[0]) / (n * n - n);
            const double LOG2E = 1.4426950408889634;
            double mult = 0.25;
            for (int k = 0; k < 5; ++k) {
                cvals[k] = (float)(-LOG2E / (bw * mult));
                mult *= 2.0;
            }
        }
    }
    gbar(ctr1);

    // ---------------- Phase D: persistent pair loop (R3 body) ----------------
    float c4 = cvals[4];
    int n16 = lane & 15, q16 = lane >> 4;
    int wr = wv >> 1, wc = wv & 1;

    // fragment LDS element offsets (cell-independent)
    int aoff[4], boff[4];
    #pragma unroll
    for (int aa = 0; aa < 4; ++aa) {
        int r = 16 * (wr * 4 + aa) + n16;
        aoff[aa] = (r * 4 + (q16 ^ ((r >> 1) & 3))) * 8;
    }
    #pragma unroll
    for (int bb = 0; bb < 4; ++bb) {
        int r = 16 * (wc * 4 + bb) + n16;
        boff[bb] = (r * 4 + (q16 ^ ((r >> 1) & 3))) * 8;
    }
    // staging chunk decode (cell-independent parts)
    int c0_ = t, c1_ = t + 256;
    int r0_ = c0_ >> 2, q0_ = (c0_ & 3) ^ ((r0_ >> 1) & 3);
    int r1_ = c1_ >> 2, q1_ = (c1_ & 3) ^ ((r1_ >> 1) & 3);
    int ldsoff0 = (0 * 256 + wv * 64) * 8;
    int ldsoff1 = (1 * 256 + wv * 64) * 8;

    for (int idx = blockIdx.x; idx < NB; idx += GRID) {
        // triangular decode, tj-major / ti-fast (R3 dispatch order)
        int tj = (int)((sqrtf(8.f * (float)idx + 1.f) - 1.f) * 0.5f);
        while ((tj + 1) * (tj + 2) / 2 <= idx) ++tj;
        while (tj * (tj + 1) / 2 > idx) --tj;
        int ti = idx - tj * (tj + 1) / 2;

        const bf16_t* gA0 = Zh + (size_t)(ti * BT + r0_) * DIM + q0_ * 8;
        const bf16_t* gA1 = Zh + (size_t)(ti * BT + r1_) * DIM + q1_ * 8;
        const bf16_t* gB0 = Zh + (size_t)(tj * BT + r0_) * DIM + q0_ * 8;
        const bf16_t* gB1 = Zh + (size_t)(tj * BT + r1_) * DIM + q1_ * 8;

        f32x4 accf[4][4];
        #pragma unroll
        for (int a = 0; a < 4; ++a)
            #pragma unroll
            for (int b = 0; b < 4; ++b)
                accf[a][b] = (f32x4){0.f, 0.f, 0.f, 0.f};

        for (int kt = 0; kt < DIM; kt += BK) {
            if (kt) __syncthreads();   // prev frag reads done before overwrite
            gload_lds16(gA0 + kt, As + ldsoff0);
            gload_lds16(gA1 + kt, As + ldsoff1);
            gload_lds16(gB0 + kt, Bs + ldsoff0);
            gload_lds16(gB1 + kt, Bs + ldsoff1);
            __syncthreads();           // drains vmcnt -> staged data visible
            bf16x8 a[4], b[4];
            #pragma unroll
            for (int aa = 0; aa < 4; ++aa) a[aa] = *(const bf16x8*)(As + aoff[aa]);
            #pragma unroll
            for (int bb = 0; bb < 4; ++bb) b[bb] = *(const bf16x8*)(Bs + boff[bb]);
            #pragma unroll
            for (int aa = 0; aa < 4; ++aa)
                #pragma unroll
                for (int bb = 0; bb < 4; ++bb)
                    accf[aa][bb] = __builtin_amdgcn_mfma_f32_16x16x32_bf16(
                        a[aa], b[bb], accf[aa][bb], 0, 0, 0);
        }

        // epilogue: D2 -> 5-bandwidth RBF via squaring chain (c_k halves per k)
        int i0 = ti * BT + wr * 64;
        int j0 = tj * BT + wc * 64;
        float sqi[4][4], sqj[4];
        #pragma unroll
        for (int aa = 0; aa < 4; ++aa)
            #pragma unroll
            for (int r = 0; r < 4; ++r)
                sqi[aa][r] = sqrow[i0 + 16 * aa + q16 * 4 + r];
        #pragma unroll
        for (int bb = 0; bb < 4; ++bb)
            sqj[bb] = sqrow[j0 + 16 * bb + n16];

        float s_local = 0.f;
        #pragma unroll
        for (int aa = 0; aa < 4; ++aa) {
            #pragma unroll
            for (int bb = 0; bb < 4; ++bb) {
                #pragma unroll
                for (int r = 0; r < 4; ++r) {
                    float d2 = fmaf(-2.f, accf[aa][bb][r], sqi[aa][r] + sqj[bb]);
                    d2 = fmaxf(d2, 0.f);
                    float e4 = EXP2F(d2 * c4);       // smallest |c|
                    float e3 = e4 * e4;
                    float e2 = e3 * e3;
                    float e1 = e2 * e2;
                    float e0 = e1 * e1;
                    s_local += e4 + e3 + e2 + e1 + e0;
                }
            }
        }
        #pragma unroll
        for (int off = 32; off > 0; off >>= 1) s_local += __shfl_down(s_local, off);
        if (lane == 0) wsum[wv] = s_local;
        __syncthreads();
        if (t == 0) {
            float bs = wsum[0] + wsum[1] + wsum[2] + wsum[3];
            double si = (ti < NT / 2) ? 1.0 : -1.0;
            double sj = (tj < NT / 2) ? 1.0 : -1.0;
            double w = si * sj * ((ti == tj) ? 1.0 : 2.0);
            atomicAdd(acc, w * (double)bs);
            __threadfence();
            unsigned old = atomicAdd(done, 1u);
            if (old == NB - 1) {                      // last tile finalizes
                __threadfence();
                double tot = atomicAdd(acc, 0.0);
                out[0] = (float)(tot / ((double)NX * (double)NX));
            }
        }
    }
}

extern "C" void kernel_launch(void* const* d_in, const int* in_sizes, int n_in,
                              void* d_out, int out_size, void* d_ws, size_t ws_size,
                              hipStream_t stream) {
    const float* X = (const float*)d_in[0];
    const float* Y = (const float*)d_in[1];
    float* out = (float*)d_out;

    hipMemsetAsync(d_ws, 0, 2112, stream);   // ctl block + colsum
    k_all<<<GRID, 256, 0, stream>>>(X, Y, out, (char*)d_ws);
}

// Round 8
// 218.841 us; speedup vs baseline: 2.0112x; 2.0112x over previous
//
#include <hip/hip_runtime.h>

#define N_ROWS 8192
#define NX     4096
#define DIM    512
#define BT     128                    // block tile (rows & cols)
#define NT     64                     // N_ROWS / BT
#define NB     (NT * (NT + 1) / 2)    // 2080 live upper-triangle tiles
#define BK     32                     // K elements per stage (64 B per row)

typedef __bf16 bf16_t;
typedef bf16_t bf16x8 __attribute__((ext_vector_type(8)));
typedef bf16_t bf16x4 __attribute__((ext_vector_type(4)));
typedef float  f32x4  __attribute__((ext_vector_type(4)));

#if __has_builtin(__builtin_amdgcn_exp2f)
  #define EXP2F __builtin_amdgcn_exp2f
#else
  #define EXP2F exp2f
#endif

// ws layout (bytes)  [first 2112 bytes zeroed by hipMemsetAsync]:
//   0     acc double (8)
//   8     done u32 (4), pad to 64
//   64    colsum[512] float (2048)          -> ends 2112
//   2112  sqrow[8192] float (32768)         -> ends 34880
//   36864 Zh[8192*512] bf16 row-major (8 MB)

__device__ __forceinline__ const float* zrow(const float* X, const float* Y, int r) {
    return (r < NX) ? (X + (size_t)r * DIM) : (Y + (size_t)(r - NX) * DIM);
}

__device__ __forceinline__ void gload_lds16(const bf16_t* g, bf16_t* l) {
    __builtin_amdgcn_global_load_lds(
        (__attribute__((address_space(1))) void*)(void*)(g),
        (__attribute__((address_space(3))) void*)(void*)(l), 16, 0, 0);
}

// blocks [0,2048): convert 4 rows to bf16 + exact fp32 row norms
// blocks [2048,2112): colsum over 128-row slab via fp32 atomics (R6-proven)
__global__ void k_prep(const float* __restrict__ X, const float* __restrict__ Y,
                       bf16_t* __restrict__ Zh, float* __restrict__ sqrow,
                       float* __restrict__ colsum) {
    int t = threadIdx.x;
    if (blockIdx.x < 2048) {
        int wv = t >> 6, lane = t & 63;
        int row = blockIdx.x * 4 + wv;
        const float4* z4 = (const float4*)zrow(X, Y, row);
        float4 a = z4[lane], b = z4[lane + 64];
        bf16x4 ha = {(bf16_t)a.x, (bf16_t)a.y, (bf16_t)a.z, (bf16_t)a.w};
        bf16x4 hb = {(bf16_t)b.x, (bf16_t)b.y, (bf16_t)b.z, (bf16_t)b.w};
        *(bf16x4*)(Zh + (size_t)row * DIM + lane * 4) = ha;
        *(bf16x4*)(Zh + (size_t)row * DIM + 256 + lane * 4) = hb;
        float s = a.x*a.x + a.y*a.y + a.z*a.z + a.w*a.w
                + b.x*b.x + b.y*b.y + b.z*b.z + b.w*b.w;
        #pragma unroll
        for (int off = 32; off > 0; off >>= 1) s += __shfl_down(s, off);
        if (lane == 0) sqrow[row] = s;
    } else {
        int b2 = blockIdx.x - 2048;        // 0..63
        int c = t * 2;
        int r0 = b2 * 128;
        float s0 = 0.f, s1 = 0.f;
        for (int r = r0; r < r0 + 128; ++r) {
            float2 v = *(const float2*)(zrow(X, Y, r) + c);
            s0 += v.x; s1 += v.y;
        }
        atomicAdd(&colsum[c], s0);
        atomicAdd(&colsum[c + 1], s1);
    }
}

// R3-exact pair body (single-buffer LDS, 2 barriers/iter, XOR-swizzled
// global_load_lds staging) + per-block bw prologue + fused finalize ticket.
// Layouts (m89/m91): A[m=lane&15][k=(lane>>4)*8+j]; C/D col=lane&15,
// row=(lane>>4)*4+reg.
__global__ __launch_bounds__(256) void k_pair(const bf16_t* __restrict__ Zh,
                                              const float* __restrict__ sqrow,
                                              const float* __restrict__ colsum,
                                              double* acc, unsigned* done,
                                              float* out) {
    int ti = blockIdx.x, tj = blockIdx.y;
    if (tj < ti) return;

    __shared__ bf16_t As[4096];   // 8 KB; doubles as double red[256] in prologue
    __shared__ bf16_t Bs[4096];   // 8 KB; doubles as double red2[256]
    __shared__ float wsum[4];
    __shared__ float c4s;

    int t = threadIdx.x, lane = t & 63, wv = t >> 6;
    int wr = wv >> 1, wc = wv & 1;

    // ---- bw prologue: S1 from sqrow, CS from colsum (L2-hot broadcast) ----
    {
        double* redA = (double*)As;
        double* redB = (double*)Bs;
        double s1 = 0.0;
        #pragma unroll 4
        for (int i = t; i < N_ROWS; i += 256) s1 += (double)sqrow[i];
        double cs = 0.0;
        for (int d = t; d < DIM; d += 256) { double v = colsum[d]; cs += v * v; }
        redA[t] = s1; redB[t] = cs; __syncthreads();
        for (int off = 128; off > 0; off >>= 1) {
            if (t < off) { redA[t] += redA[t + off]; redB[t] += redB[t + off]; }
            __syncthreads();
        }
        if (t == 0) {
            double n = (double)N_ROWS;
            double bw = (2.0 * n * redA[0] - 2.0 * redB[0]) / (n * n - n);
            c4s = (float)(-1.4426950408889634 / (bw * 4.0));  // smallest |c|
        }
        __syncthreads();
    }
    float c4 = c4s;

    // staging chunks: c = h*256+t; row r=c>>2, phys slot sq=c&3 holds logical
    // chunk q = sq ^ ((r>>1)&3)  -> 64 B-coalesced per row, swizzled in LDS
    const bf16_t* gA[2]; const bf16_t* gB[2];
    int ldsoff[2];
    #pragma unroll
    for (int h = 0; h < 2; ++h) {
        int c = h * 256 + t;
        int r = c >> 2, sq = c & 3;
        int q = sq ^ ((r >> 1) & 3);
        gA[h] = Zh + (size_t)(ti * BT + r) * DIM + q * 8;
        gB[h] = Zh + (size_t)(tj * BT + r) * DIM + q * 8;
        ldsoff[h] = (h * 256 + wv * 64) * 8;    // wave-uniform base (lane*16B implicit)
    }

    // fragment LDS element offsets
    int n16 = lane & 15, q16 = lane >> 4;
    int aoff[4], boff[4];
    #pragma unroll
    for (int aa = 0; aa < 4; ++aa) {
        int r = 16 * (wr * 4 + aa) + n16;
        aoff[aa] = (r * 4 + (q16 ^ ((r >> 1) & 3))) * 8;
    }
    #pragma unroll
    for (int bb = 0; bb < 4; ++bb) {
        int r = 16 * (wc * 4 + bb) + n16;
        boff[bb] = (r * 4 + (q16 ^ ((r >> 1) & 3))) * 8;
    }

    f32x4 accf[4][4];
    #pragma unroll
    for (int a = 0; a < 4; ++a)
        #pragma unroll
        for (int b = 0; b < 4; ++b)
            accf[a][b] = (f32x4){0.f, 0.f, 0.f, 0.f};

    for (int kt = 0; kt < DIM; kt += BK) {
        if (kt) __syncthreads();   // prev frag reads done before overwrite
        #pragma unroll
        for (int h = 0; h < 2; ++h) {
            gload_lds16(gA[h] + kt, As + ldsoff[h]);
            gload_lds16(gB[h] + kt, Bs + ldsoff[h]);
        }
        __syncthreads();           // drains vmcnt -> staged data visible
        bf16x8 a[4], b[4];
        #pragma unroll
        for (int aa = 0; aa < 4; ++aa) a[aa] = *(const bf16x8*)(As + aoff[aa]);
        #pragma unroll
        for (int bb = 0; bb < 4; ++bb) b[bb] = *(const bf16x8*)(Bs + boff[bb]);
        #pragma unroll
        for (int aa = 0; aa < 4; ++aa)
            #pragma unroll
            for (int bb = 0; bb < 4; ++bb)
                accf[aa][bb] = __builtin_amdgcn_mfma_f32_16x16x32_bf16(
                    a[aa], b[bb], accf[aa][bb], 0, 0, 0);
    }

    // epilogue: D2 -> 5-bandwidth RBF via squaring chain (c_k halves per k)
    int i0 = ti * BT + wr * 64;
    int j0 = tj * BT + wc * 64;
    float sqi[4][4], sqj[4];
    #pragma unroll
    for (int aa = 0; aa < 4; ++aa)
        #pragma unroll
        for (int r = 0; r < 4; ++r)
            sqi[aa][r] = sqrow[i0 + 16 * aa + q16 * 4 + r];
    #pragma unroll
    for (int bb = 0; bb < 4; ++bb)
        sqj[bb] = sqrow[j0 + 16 * bb + n16];

    float s_local = 0.f;
    #pragma unroll
    for (int aa = 0; aa < 4; ++aa) {
        #pragma unroll
        for (int bb = 0; bb < 4; ++bb) {
            #pragma unroll
            for (int r = 0; r < 4; ++r) {
                float d2 = fmaf(-2.f, accf[aa][bb][r], sqi[aa][r] + sqj[bb]);
                d2 = fmaxf(d2, 0.f);
                float e4 = EXP2F(d2 * c4);       // smallest |c|
                float e3 = e4 * e4;
                float e2 = e3 * e3;
                float e1 = e2 * e2;
                float e0 = e1 * e1;
                s_local += e4 + e3 + e2 + e1 + e0;
            }
        }
    }
    #pragma unroll
    for (int off = 32; off > 0; off >>= 1) s_local += __shfl_down(s_local, off);
    if (lane == 0) wsum[wv] = s_local;
    __syncthreads();
    if (t == 0) {
        float bs = wsum[0] + wsum[1] + wsum[2] + wsum[3];
        double si = (ti < NT / 2) ? 1.0 : -1.0;
        double sj = (tj < NT / 2) ? 1.0 : -1.0;
        double w = si * sj * ((ti == tj) ? 1.0 : 2.0);
        atomicAdd(acc, w * (double)bs);
        __threadfence();
        unsigned old = atomicAdd(done, 1u);
        if (old == NB - 1) {                      // last live block finalizes
            __threadfence();
            double tot = atomicAdd(acc, 0.0);
            out[0] = (float)(tot / ((double)NX * (double)NX));
        }
    }
}

extern "C" void kernel_launch(void* const* d_in, const int* in_sizes, int n_in,
                              void* d_out, int out_size, void* d_ws, size_t ws_size,
                              hipStream_t stream) {
    const float* X = (const float*)d_in[0];
    const float* Y = (const float*)d_in[1];
    float* out = (float*)d_out;

    double*   acc    = (double*)d_ws;
    unsigned* done   = (unsigned*)((char*)d_ws + 8);
    float*    colsum = (float*)((char*)d_ws + 64);
    float*    sqrow  = (float*)((char*)d_ws + 2112);
    bf16_t*   Zh     = (bf16_t*)((char*)d_ws + 36864);

    hipMemsetAsync(d_ws, 0, 2112, stream);   // acc + done + colsum
    k_prep<<<2112, 256, 0, stream>>>(X, Y, Zh, sqrow, colsum);
    k_pair<<<dim3(NT, NT), 256, 0, stream>>>(Zh, sqrow, colsum, acc, done, out);
}